// Round 18
// baseline (123.045 us; speedup 1.0000x reference)
//
#include <hip/hip_runtime.h>
#include <math.h>

// Problem constants (ViT-Base): B=4, S=1024, D=768, H=12, HD=64
constexpr float SCALE = 0.125f;               // 1/sqrt(64)

typedef __attribute__((ext_vector_type(8))) short bf8;            // 8 bf16 (4 VGPRs)
typedef __attribute__((ext_vector_type(8))) unsigned short u16x8;
typedef __attribute__((ext_vector_type(4))) float f32x4;

static __device__ __forceinline__ unsigned short f2bf(float f) {
    unsigned int u = __float_as_uint(f);
    u += 0x7fffu + ((u >> 16) & 1u);          // round-to-nearest-even
    return (unsigned short)(u >> 16);
}
static __device__ __forceinline__ float bf2f(unsigned short h) {
    return __uint_as_float(((unsigned int)h) << 16);
}
static __device__ __forceinline__ bf8 ld8(const unsigned short* p) {
    return *reinterpret_cast<const bf8*>(p);
}
static __device__ __forceinline__ unsigned int cvtpk(float lo, float hi) {
    unsigned int r;
    asm("v_cvt_pk_bf16_f32 %0, %1, %2" : "=v"(r) : "v"(lo), "v"(hi));
    return r;
}

// ---------------------------------------------------------------------------
// Fused weight transpose+convert: Wq->WTq, Wv->WTv. 288 blocks flat.
// WT[n][k] = bf16(W[k][n])
// ---------------------------------------------------------------------------
__global__ __launch_bounds__(256)
void k_prep(const float* __restrict__ Wq, const float* __restrict__ Wv,
            unsigned short* __restrict__ WTq, unsigned short* __restrict__ WTv)
{
    __shared__ unsigned short T[64 * 72];
    const int bid = blockIdx.x;
    const bool isQ = (bid < 144);
    const int lb = isQ ? bid : bid - 144;
    const float* __restrict__ W = isQ ? Wq : Wv;
    unsigned short* __restrict__ WT = isQ ? WTq : WTv;
    const int n0 = (lb % 12) * 64;
    const int k0 = (lb / 12) * 64;
    const int tid = threadIdx.x;
    const int r  = tid >> 2;          // k within tile
    const int c0 = (tid & 3) * 16;    // n within tile
    const float* src = &W[(size_t)(k0 + r) * 768 + n0 + c0];
    #pragma unroll
    for (int q = 0; q < 4; ++q) {
        const float4 v = *reinterpret_cast<const float4*>(src + q * 4);
        uint2 pk;
        pk.x = cvtpk(v.x, v.y);
        pk.y = cvtpk(v.z, v.w);
        *reinterpret_cast<uint2*>(&T[r * 72 + c0 + q * 4]) = pk;
    }
    __syncthreads();
    const int n  = tid >> 2;          // n within tile
    const int kc = (tid & 3) * 16;    // k within tile
    u16x8 o0, o1;
    #pragma unroll
    for (int i = 0; i < 8; ++i) o0[i] = T[(kc + i) * 72 + n];
    #pragma unroll
    for (int i = 0; i < 8; ++i) o1[i] = T[(kc + 8 + i) * 72 + n];
    unsigned short* dst = WT + (size_t)(n0 + n) * 768 + k0 + kc;
    *reinterpret_cast<u16x8*>(dst)     = o0;
    *reinterpret_cast<u16x8*>(dst + 8) = o1;
}

// ---------------------------------------------------------------------------
// GEMM 1 (MFMA bf16): C = X @ WT^T + bias. Tile 64x128, BK=128, 6 k-steps,
// issue-early/write-late register staging. grid (64,12) = 768 blocks.
// ---------------------------------------------------------------------------
__global__ __launch_bounds__(256)
void k_gemm_qv(const float* __restrict__ X,
               const unsigned short* __restrict__ WTq,
               const unsigned short* __restrict__ WTv,
               const float* __restrict__ bq, const float* __restrict__ bv,
               float* __restrict__ mq1, float* __restrict__ mq2,
               unsigned short* __restrict__ qb, unsigned short* __restrict__ mvb)
{
    __shared__ unsigned short As[64 * 136];
    __shared__ unsigned short Bs[128 * 136];
    const int m0 = blockIdx.x * 64;
    const bool isQ = (blockIdx.y < 6);
    const int n0 = (isQ ? blockIdx.y : blockIdx.y - 6) * 128;
    const unsigned short* __restrict__ WT = isQ ? WTq : WTv;
    const float* __restrict__ bias = isQ ? bq : bv;
    const int tid = threadIdx.x;
    const int wave = tid >> 6, lane = tid & 63, lm = lane & 15, lg = lane >> 4;
    const int wn = wave;

    f32x4 acc[4][2];
    #pragma unroll
    for (int mi = 0; mi < 4; ++mi)
        #pragma unroll
        for (int ni = 0; ni < 2; ++ni) acc[mi][ni] = (f32x4){0.f, 0.f, 0.f, 0.f};

    float4 ar[8];
    u16x8  br[8];

    // prologue: stage k-step 0
    #pragma unroll
    for (int it = 0; it < 8; ++it) {
        const int idx = tid + it * 256;
        ar[it] = *reinterpret_cast<const float4*>(
            &X[(size_t)(m0 + (idx >> 5)) * 768 + (idx & 31) * 4]);
        br[it] = *reinterpret_cast<const u16x8*>(
            &WT[(size_t)(n0 + (idx >> 4)) * 768 + (idx & 15) * 8]);
    }
    #pragma unroll
    for (int it = 0; it < 8; ++it) {
        const int idx = tid + it * 256;
        uint2 pk;
        pk.x = cvtpk(ar[it].x, ar[it].y);
        pk.y = cvtpk(ar[it].z, ar[it].w);
        *reinterpret_cast<uint2*>(&As[(idx >> 5) * 136 + (idx & 31) * 4]) = pk;
        *reinterpret_cast<u16x8*>(&Bs[(idx >> 4) * 136 + (idx & 15) * 8]) = br[it];
    }
    __syncthreads();

    for (int step = 0; step < 6; ++step) {
        const bool pf = (step < 5);
        if (pf) {
            const int k0 = (step + 1) * 128;
            #pragma unroll
            for (int it = 0; it < 8; ++it) {
                const int idx = tid + it * 256;
                ar[it] = *reinterpret_cast<const float4*>(
                    &X[(size_t)(m0 + (idx >> 5)) * 768 + k0 + (idx & 31) * 4]);
                br[it] = *reinterpret_cast<const u16x8*>(
                    &WT[(size_t)(n0 + (idx >> 4)) * 768 + k0 + (idx & 15) * 8]);
            }
        }
        #pragma unroll
        for (int ks = 0; ks < 4; ++ks) {
            bf8 af[4], bfr[2];
            #pragma unroll
            for (int mi = 0; mi < 4; ++mi)
                af[mi] = *reinterpret_cast<const bf8*>(
                    &As[(mi * 16 + lm) * 136 + ks * 32 + lg * 8]);
            #pragma unroll
            for (int ni = 0; ni < 2; ++ni)
                bfr[ni] = *reinterpret_cast<const bf8*>(
                    &Bs[(wn * 32 + ni * 16 + lm) * 136 + ks * 32 + lg * 8]);
            #pragma unroll
            for (int mi = 0; mi < 4; ++mi)
                #pragma unroll
                for (int ni = 0; ni < 2; ++ni)
                    acc[mi][ni] = __builtin_amdgcn_mfma_f32_16x16x32_bf16(
                        af[mi], bfr[ni], acc[mi][ni], 0, 0, 0);
        }
        __syncthreads();
        if (pf) {
            #pragma unroll
            for (int it = 0; it < 8; ++it) {
                const int idx = tid + it * 256;
                uint2 pk;
                pk.x = cvtpk(ar[it].x, ar[it].y);
                pk.y = cvtpk(ar[it].z, ar[it].w);
                *reinterpret_cast<uint2*>(&As[(idx >> 5) * 136 + (idx & 31) * 4]) = pk;
                *reinterpret_cast<u16x8*>(&Bs[(idx >> 4) * 136 + (idx & 15) * 8]) = br[it];
            }
        }
        __syncthreads();
    }
    #pragma unroll
    for (int ni = 0; ni < 2; ++ni) {
        const int c = n0 + wn * 32 + ni * 16 + lm;
        const float bcol = bias[c];
        #pragma unroll
        for (int mi = 0; mi < 4; ++mi)
            #pragma unroll
            for (int j = 0; j < 4; ++j) {
                const int r = m0 + mi * 16 + lg * 4 + j;
                const float v = acc[mi][ni][j] + bcol;
                const size_t off = (size_t)r * 768 + c;
                if (isQ) {
                    mq1[off] = v;
                    mq2[off] = v;
                    qb[off]  = f2bf(v);
                } else {
                    mvb[off] = f2bf(v);
                }
            }
    }
}

// ---------------------------------------------------------------------------
// GEMM 2 (MFMA bf16) + fused final reduction: flat grid 769.
// Blocks 0..767: att = ctxb @ WTo^T + bo (64x64 tile, BK=128, reg-prefetch).
// Block 768: deterministic reduction of t1p/t2p/regp -> tr, reg scalars.
// ---------------------------------------------------------------------------
__global__ __launch_bounds__(256)
void k_gemm_one(const unsigned short* __restrict__ Xb,
                const unsigned short* __restrict__ WT,
                const float* __restrict__ bias, float* __restrict__ out,
                const float* __restrict__ t1p, const float* __restrict__ t2p,
                const float* __restrict__ regp, float* __restrict__ out_tr,
                float* __restrict__ out_reg)
{
    __shared__ unsigned short As[64 * 136];
    __shared__ unsigned short Bs[64 * 136];
    __shared__ float R1[256];
    __shared__ float R2[256];
    __shared__ float R3[256];
    const int tid = threadIdx.x;

    if (blockIdx.x == 768) {
        // ---- fused k_final -------------------------------------------------
        float s1 = 0.f, s2 = 0.f, s3 = 0.f;
        for (int i = tid; i < 768; i += 256) s2 += t2p[i];
        if (tid < 48) { s1 = t1p[tid]; s3 = regp[tid]; }
        R1[tid] = s1; R2[tid] = s2; R3[tid] = s3;
        __syncthreads();
        for (int w = 128; w >= 1; w >>= 1) {
            if (tid < w) { R1[tid] += R1[tid + w]; R2[tid] += R2[tid + w]; R3[tid] += R3[tid + w]; }
            __syncthreads();
        }
        if (tid == 0) {
            *out_tr  = fabsf(R1[0] - R2[0]) / 3072.f;
            *out_reg = R3[0] / 3072.f;
        }
        return;
    }

    const int m0 = (blockIdx.x & 63) * 64;
    const int n0 = (blockIdx.x >> 6) * 64;
    const int w = tid >> 6, lane = tid & 63, lm = lane & 15, lg = lane >> 4;

    f32x4 acc[4];
    #pragma unroll
    for (int ni = 0; ni < 4; ++ni) acc[ni] = (f32x4){0.f, 0.f, 0.f, 0.f};

    u16x8 ara[4], arb[4];
    // prologue: stage k-step 0
    #pragma unroll
    for (int it = 0; it < 4; ++it) {
        const int idx = tid + it * 256;
        ara[it] = *reinterpret_cast<const u16x8*>(
            &Xb[(size_t)(m0 + (idx >> 4)) * 768 + (idx & 15) * 8]);
        arb[it] = *reinterpret_cast<const u16x8*>(
            &WT[(size_t)(n0 + (idx >> 4)) * 768 + (idx & 15) * 8]);
    }
    #pragma unroll
    for (int it = 0; it < 4; ++it) {
        const int idx = tid + it * 256;
        *reinterpret_cast<u16x8*>(&As[(idx >> 4) * 136 + (idx & 15) * 8]) = ara[it];
        *reinterpret_cast<u16x8*>(&Bs[(idx >> 4) * 136 + (idx & 15) * 8]) = arb[it];
    }
    __syncthreads();

    for (int step = 0; step < 6; ++step) {
        const bool pf = (step < 5);
        if (pf) {
            const int k0 = (step + 1) * 128;
            #pragma unroll
            for (int it = 0; it < 4; ++it) {
                const int idx = tid + it * 256;
                ara[it] = *reinterpret_cast<const u16x8*>(
                    &Xb[(size_t)(m0 + (idx >> 4)) * 768 + k0 + (idx & 15) * 8]);
                arb[it] = *reinterpret_cast<const u16x8*>(
                    &WT[(size_t)(n0 + (idx >> 4)) * 768 + k0 + (idx & 15) * 8]);
            }
        }
        #pragma unroll
        for (int ks = 0; ks < 4; ++ks) {
            const bf8 af = *reinterpret_cast<const bf8*>(
                &As[(w * 16 + lm) * 136 + ks * 32 + lg * 8]);
            #pragma unroll
            for (int ni = 0; ni < 4; ++ni) {
                const bf8 bfr = *reinterpret_cast<const bf8*>(
                    &Bs[(ni * 16 + lm) * 136 + ks * 32 + lg * 8]);
                acc[ni] = __builtin_amdgcn_mfma_f32_16x16x32_bf16(af, bfr, acc[ni], 0, 0, 0);
            }
        }
        __syncthreads();
        if (pf) {
            #pragma unroll
            for (int it = 0; it < 4; ++it) {
                const int idx = tid + it * 256;
                *reinterpret_cast<u16x8*>(&As[(idx >> 4) * 136 + (idx & 15) * 8]) = ara[it];
                *reinterpret_cast<u16x8*>(&Bs[(idx >> 4) * 136 + (idx & 15) * 8]) = arb[it];
            }
        }
        __syncthreads();
    }
    #pragma unroll
    for (int ni = 0; ni < 4; ++ni) {
        const int c = n0 + ni * 16 + lm;
        const float bcol = bias[c];
        #pragma unroll
        for (int j = 0; j < 4; ++j) {
            const int r = m0 + w * 16 + lg * 4 + j;
            out[(size_t)r * 768 + c] = acc[ni][j] + bcol;
        }
    }
}

// ---------------------------------------------------------------------------
// Pass 1 fused: V-tile transpose (mvb->vT) + column sumsq partials + QQ^T
// row-sums a_s = 1/(sum_t exp(sc/8)). LDS-staged K with BK=128 tiles
// (8 chunks, half the barriers), double-buffered. grid 768 flat, swizzled.
// ---------------------------------------------------------------------------
__global__ __launch_bounds__(256)
void k_pass1T(const unsigned short* __restrict__ qb,
              const unsigned short* __restrict__ mvb,
              unsigned short* __restrict__ vT,
              float* __restrict__ a, float* __restrict__ nrmp)
{
    __shared__ __align__(16) unsigned short Kb[2][128 * 72];
    const int bid = blockIdx.x;
    const int st = (bid >> 3) & 15;
    const int bh = (bid & 7) + 8 * (bid >> 7);
    const int b = bh / 12, h = bh % 12;
    const int s0 = st * 64;
    const int tid = threadIdx.x;
    const int w = tid >> 6, lane = tid & 63, lm = lane & 15, lg = lane >> 4;
    const size_t qoff = (size_t)(b * 1024) * 768 + h * 64;

    // ---- prologue: transpose V tile + norm partials (uses Kb[0] as scratch)
    {
        const int r  = tid >> 2;
        const int c0 = (tid & 3) * 16;
        const unsigned short* src = mvb + (size_t)(b * 1024 + s0 + r) * 768 + h * 64 + c0;
        const u16x8 x0 = *reinterpret_cast<const u16x8*>(src);
        const u16x8 x1 = *reinterpret_cast<const u16x8*>(src + 8);
        *reinterpret_cast<u16x8*>(&Kb[0][r * 72 + c0])     = x0;
        *reinterpret_cast<u16x8*>(&Kb[0][r * 72 + c0 + 8]) = x1;
        __syncthreads();
        const int dd  = tid >> 2;
        const int sc0 = (tid & 3) * 16;
        u16x8 o0, o1;
        float ps = 0.f;
        #pragma unroll
        for (int k = 0; k < 8; ++k) {
            o0[k] = Kb[0][(sc0 + k) * 72 + dd];
            const float v = bf2f(o0[k]);
            ps = fmaf(v, v, ps);
        }
        #pragma unroll
        for (int k = 0; k < 8; ++k) {
            o1[k] = Kb[0][(sc0 + 8 + k) * 72 + dd];
            const float v = bf2f(o1[k]);
            ps = fmaf(v, v, ps);
        }
        ps += __shfl_xor(ps, 1);
        ps += __shfl_xor(ps, 2);
        if ((tid & 3) == 0) nrmp[(size_t)(bh * 16 + st) * 64 + dd] = ps;
        unsigned short* dst = vT + (size_t)bh * 65536 + (size_t)dd * 1024 + s0 + sc0;
        *reinterpret_cast<u16x8*>(dst)     = o0;
        *reinterpret_cast<u16x8*>(dst + 8) = o1;
        __syncthreads();
    }

    // ---- pass1 main: QQ^T row sums over BK=128 tiles -----------------------
    const unsigned short* srow_p = qb + qoff + (size_t)(s0 + 16 * w + lm) * 768;
    const bf8 qs0 = ld8(srow_p + 8 * lg);
    const bf8 qs1 = ld8(srow_p + 32 + 8 * lg);
    const f32x4 z = {0.f, 0.f, 0.f, 0.f};
    float r = 0.f;

    u16x8 kr[4];
    #pragma unroll
    for (int it = 0; it < 4; ++it) {
        const int idx = tid + it * 256;
        kr[it] = *reinterpret_cast<const u16x8*>(
            qb + qoff + (size_t)(idx >> 3) * 768 + (idx & 7) * 8);
    }
    #pragma unroll
    for (int it = 0; it < 4; ++it) {
        const int idx = tid + it * 256;
        *reinterpret_cast<u16x8*>(&Kb[0][(idx >> 3) * 72 + (idx & 7) * 8]) = kr[it];
    }
    __syncthreads();
    int cur = 0;

    for (int tt = 0; tt < 8; ++tt) {
        const bool pf = (tt < 7);
        if (pf) {
            #pragma unroll
            for (int it = 0; it < 4; ++it) {
                const int idx = tid + it * 256;
                kr[it] = *reinterpret_cast<const u16x8*>(
                    qb + qoff + (size_t)((tt + 1) * 128 + (idx >> 3)) * 768 + (idx & 7) * 8);
            }
        }
        #pragma unroll
        for (int nf = 0; nf < 8; ++nf) {
            const bf8 ka0 = *reinterpret_cast<const bf8*>(
                &Kb[cur][(16 * nf + lm) * 72 + 8 * lg]);
            const bf8 ka1 = *reinterpret_cast<const bf8*>(
                &Kb[cur][(16 * nf + lm) * 72 + 32 + 8 * lg]);
            f32x4 ef = __builtin_amdgcn_mfma_f32_16x16x32_bf16(ka0, qs0, z, 0, 0, 0);
            ef = __builtin_amdgcn_mfma_f32_16x16x32_bf16(ka1, qs1, ef, 0, 0, 0);
            r += __expf(ef[0] * SCALE) + __expf(ef[1] * SCALE)
               + __expf(ef[2] * SCALE) + __expf(ef[3] * SCALE);
        }
        if (pf) {
            #pragma unroll
            for (int it = 0; it < 4; ++it) {
                const int idx = tid + it * 256;
                *reinterpret_cast<u16x8*>(
                    &Kb[cur ^ 1][(idx >> 3) * 72 + (idx & 7) * 8]) = kr[it];
            }
        }
        __syncthreads();
        cur ^= 1;
    }
    r += __shfl_xor(r, 16);
    r += __shfl_xor(r, 32);
    if (lg == 0) a[(size_t)bh * 1024 + s0 + 16 * w + lm] = 1.f / r;
}

// ---------------------------------------------------------------------------
// Pass 2 (MFMA, swapped QK + F-trick, LDS-staged K/V, double-buffered):
// F = E*(a_s+a_t); ctx = 0.5*F@V; dvec = 0.5*rowsum(F). invn computed in
// prologue from nrmp (st==0 blocks publish it to global for k_regfin).
// grid 768 flat, XCD-swizzled.
// ---------------------------------------------------------------------------
__global__ __launch_bounds__(256)
void k_pass2(const unsigned short* __restrict__ qb,
             const unsigned short* __restrict__ vT,
             const unsigned short* __restrict__ mvb,
             const float* __restrict__ a,
             const float* __restrict__ nrmp,
             float* __restrict__ invn_out,
             unsigned short* __restrict__ ctxb,
             float* __restrict__ t2p)
{
    __shared__ __align__(16) unsigned short Kb[2][64 * 72];
    __shared__ __align__(16) unsigned short Vb[2][64 * 72];
    __shared__ __align__(16) unsigned short F_lds[4 * 16 * 72];  // per-wave [16][72]
    __shared__ float red[256];
    __shared__ float inv_sh[64];
    const int bid = blockIdx.x;
    const int st = (bid >> 3) & 15;
    const int bh = (bid & 7) + 8 * (bid >> 7);
    const int b = bh / 12, h = bh % 12;
    const int s0 = st * 64;
    const int tid = threadIdx.x;
    const int w = tid >> 6, lane = tid & 63, lm = lane & 15, lg = lane >> 4;
    const size_t qoff = (size_t)(b * 1024) * 768 + h * 64;
    const unsigned short* srow_p = qb + qoff + (size_t)(s0 + 16 * w + lm) * 768;
    const bf8 qs0 = ld8(srow_p + 8 * lg);
    const bf8 qs1 = ld8(srow_p + 32 + 8 * lg);
    const unsigned short* vbase = vT + (size_t)bh * 65536;
    const float* abase = a + (size_t)bh * 1024;
    const float a_s = abase[s0 + 16 * w + lm];     // own-row a (A-operand row = lm)
    unsigned short* Frow = &F_lds[w * 1152 + lm * 72];  // lane's own s-row region
    const f32x4 z = {0.f, 0.f, 0.f, 0.f};
    f32x4 acc[4];
    #pragma unroll
    for (int nf = 0; nf < 4; ++nf) acc[nf] = z;
    float sF = 0.f;
    const int sr = tid >> 2;          // row within tile (t for K, d for V)
    const int sc = (tid & 3) << 4;    // 16-col group

    // invn from nrmp (tid<64); 16 independent L2 loads, overlapped w/ staging
    if (tid < 64) {
        float s = 0.f;
        #pragma unroll
        for (int t = 0; t < 16; ++t) s += nrmp[(size_t)(bh * 16 + t) * 64 + tid];
        const float iv = 1.f / fmaxf(sqrtf(s), 1e-12f);
        inv_sh[tid] = iv;
        if (st == 0) invn_out[bh * 64 + tid] = iv;
    }

    u16x8 kr0 = *reinterpret_cast<const u16x8*>(qb + qoff + (size_t)sr * 768 + sc);
    u16x8 kr1 = *reinterpret_cast<const u16x8*>(qb + qoff + (size_t)sr * 768 + sc + 8);
    u16x8 vr0 = *reinterpret_cast<const u16x8*>(vbase + (size_t)sr * 1024 + sc);
    u16x8 vr1 = *reinterpret_cast<const u16x8*>(vbase + (size_t)sr * 1024 + sc + 8);
    *reinterpret_cast<u16x8*>(&Kb[0][sr * 72 + sc])     = kr0;
    *reinterpret_cast<u16x8*>(&Kb[0][sr * 72 + sc + 8]) = kr1;
    *reinterpret_cast<u16x8*>(&Vb[0][sr * 72 + sc])     = vr0;
    *reinterpret_cast<u16x8*>(&Vb[0][sr * 72 + sc + 8]) = vr1;
    __syncthreads();
    int cur = 0;

    for (int tt = 0; tt < 16; ++tt) {
        const int t0 = tt * 64;
        if (tt < 15) {
            const size_t kg = qoff + (size_t)(t0 + 64 + sr) * 768 + sc;
            kr0 = *reinterpret_cast<const u16x8*>(qb + kg);
            kr1 = *reinterpret_cast<const u16x8*>(qb + kg + 8);
            const size_t vg = (size_t)sr * 1024 + t0 + 64 + sc;
            vr0 = *reinterpret_cast<const u16x8*>(vbase + vg);
            vr1 = *reinterpret_cast<const u16x8*>(vbase + vg + 8);
        }
        // ---- QK^T (swapped): lane holds sc[s=16w+lm][t=16nf+4lg+j] ---------
        f32x4 ef[4];
        #pragma unroll
        for (int nf = 0; nf < 4; ++nf) {
            const bf8 ka0 = *reinterpret_cast<const bf8*>(
                &Kb[cur][(16 * nf + lm) * 72 + 8 * lg]);
            const bf8 ka1 = *reinterpret_cast<const bf8*>(
                &Kb[cur][(16 * nf + lm) * 72 + 32 + 8 * lg]);
            ef[nf] = __builtin_amdgcn_mfma_f32_16x16x32_bf16(ka0, qs0, z, 0, 0, 0);
            ef[nf] = __builtin_amdgcn_mfma_f32_16x16x32_bf16(ka1, qs1, ef[nf], 0, 0, 0);
        }
        // ---- F = exp(sc/8)*(a_s + a_t); write own row to LDS ---------------
        #pragma unroll
        for (int nf = 0; nf < 4; ++nf) {
            const float4 af = *reinterpret_cast<const float4*>(
                abase + t0 + 16 * nf + 4 * lg);
            const float f0 = __expf(ef[nf][0] * SCALE) * (a_s + af.x);
            const float f1 = __expf(ef[nf][1] * SCALE) * (a_s + af.y);
            const float f2 = __expf(ef[nf][2] * SCALE) * (a_s + af.z);
            const float f3 = __expf(ef[nf][3] * SCALE) * (a_s + af.w);
            sF += (f0 + f1) + (f2 + f3);
            uint2 pk;
            pk.x = cvtpk(f0, f1);
            pk.y = cvtpk(f2, f3);
            *reinterpret_cast<uint2*>(&Frow[16 * nf + 4 * lg]) = pk;
        }
        // ---- PV: A-frag = own row from LDS (b128), B-frag = Vb LDS ---------
        #pragma unroll
        for (int ks = 0; ks < 2; ++ks) {
            const bf8 fa = *reinterpret_cast<const bf8*>(&Frow[32 * ks + 8 * lg]);
            #pragma unroll
            for (int nf = 0; nf < 4; ++nf) {
                const bf8 vfr = *reinterpret_cast<const bf8*>(
                    &Vb[cur][(16 * nf + lm) * 72 + 32 * ks + 8 * lg]);
                acc[nf] = __builtin_amdgcn_mfma_f32_16x16x32_bf16(fa, vfr, acc[nf], 0, 0, 0);
            }
        }
        if (tt < 15) {
            *reinterpret_cast<u16x8*>(&Kb[cur ^ 1][sr * 72 + sc])     = kr0;
            *reinterpret_cast<u16x8*>(&Kb[cur ^ 1][sr * 72 + sc + 8]) = kr1;
            *reinterpret_cast<u16x8*>(&Vb[cur ^ 1][sr * 72 + sc])     = vr0;
            *reinterpret_cast<u16x8*>(&Vb[cur ^ 1][sr * 72 + sc + 8]) = vr1;
        }
        __syncthreads();
        cur ^= 1;
    }
    sF += __shfl_xor(sF, 16);
    sF += __shfl_xor(sF, 32);

    float t2 = 0.f;
    #pragma unroll
    for (int j = 0; j < 4; ++j) {
        const int srow = s0 + 16 * w + 4 * lg + j;
        const float sFj = __shfl(sF, 4 * lg + j);
        const float rdv = 2.f / sFj;                // 1/dvec
        const size_t rowoff = (size_t)(b * 1024 + srow) * 768 + h * 64;
        #pragma unroll
        for (int nf = 0; nf < 4; ++nf) {
            const int d = lm + 16 * nf;
            const float iv = inv_sh[d];
            const float cf = 0.5f * acc[nf][j];
            ctxb[rowoff + d] = f2bf(cf);
            const float vv = bf2f(mvb[rowoff + d]);
            t2 = fmaf(vv * cf, iv * iv * rdv, t2);
        }
    }
    red[tid] = t2;
    __syncthreads();
    for (int k = 128; k >= 1; k >>= 1) {
        if (tid < k) red[tid] += red[tid + k];
        __syncthreads();
    }
    if (tid == 0) t2p[bh * 16 + st] = red[0];
}

// ---------------------------------------------------------------------------
// Merged: Gram partials (blocks 0..383) + Wo transpose (blocks 384..527).
// WTo is written into the (dead after pass2) mvb slot — no vT conflict.
// ---------------------------------------------------------------------------
__global__ __launch_bounds__(256)
void k_regwt(const unsigned short* __restrict__ vT, float* __restrict__ Gpart,
             const float* __restrict__ Wo, unsigned short* __restrict__ WTo)
{
    __shared__ unsigned short T[64 * 72];
    const int bid = blockIdx.x;
    const int tid = threadIdx.x;
    if (bid < 384) {
        // ---- Gram partial: bh = bid>>3, q = bid&7, K=128 slice --------------
        const int bh = bid >> 3;
        const int q  = bid & 7;
        const int w = tid >> 6, lane = tid & 63, lm = lane & 15, lg = lane >> 4;
        const unsigned short* base = vT + (size_t)bh * 65536;
        const unsigned short* arowp = base + (size_t)(16 * w + lm) * 1024;
        const f32x4 z = {0.f, 0.f, 0.f, 0.f};
        f32x4 acc[4];
        #pragma unroll
        for (int nf = 0; nf < 4; ++nf) acc[nf] = z;
        #pragma unroll
        for (int kk = 0; kk < 4; ++kk) {
            const int t0 = (q * 4 + kk) * 32 + 8 * lg;
            const bf8 av = ld8(arowp + t0);
            #pragma unroll
            for (int nf = 0; nf < 4; ++nf) {
                const bf8 bv = ld8(base + (size_t)(lm + 16 * nf) * 1024 + t0);
                acc[nf] = __builtin_amdgcn_mfma_f32_16x16x32_bf16(av, bv, acc[nf], 0, 0, 0);
            }
        }
        float* gdst = Gpart + (size_t)(bh * 8 + q) * 4096;
        #pragma unroll
        for (int nf = 0; nf < 4; ++nf) {
            const int d2 = lm + 16 * nf;
            #pragma unroll
            for (int j = 0; j < 4; ++j) {
                const int d1 = 16 * w + 4 * lg + j;
                gdst[d1 * 64 + d2] = acc[nf][j];
            }
        }
    } else {
        // ---- Wo transpose tile ----------------------------------------------
        const int lb = bid - 384;
        const int n0 = (lb % 12) * 64;
        const int k0 = (lb / 12) * 64;
        const int r  = tid >> 2;
        const int c0 = (tid & 3) * 16;
        const float* src = &Wo[(size_t)(k0 + r) * 768 + n0 + c0];
        #pragma unroll
        for (int q = 0; q < 4; ++q) {
            const float4 v = *reinterpret_cast<const float4*>(src + q * 4);
            uint2 pk;
            pk.x = cvtpk(v.x, v.y);
            pk.y = cvtpk(v.z, v.w);
            *reinterpret_cast<uint2*>(&T[r * 72 + c0 + q * 4]) = pk;
        }
        __syncthreads();
        const int n  = tid >> 2;
        const int kc = (tid & 3) * 16;
        u16x8 o0, o1;
        #pragma unroll
        for (int i = 0; i < 8; ++i) o0[i] = T[(kc + i) * 72 + n];
        #pragma unroll
        for (int i = 0; i < 8; ++i) o1[i] = T[(kc + 8 + i) * 72 + n];
        unsigned short* dst = WTo + (size_t)(n0 + n) * 768 + k0 + kc;
        *reinterpret_cast<u16x8*>(dst)     = o0;
        *reinterpret_cast<u16x8*>(dst + 8) = o1;
    }
}

// ---------------------------------------------------------------------------
// Gram finalize + t1: sum 8 Gram partials, scale by invn, sum (G - I)^2;
// also t1[bh] = sum_d nrmp_sum(d) * invn(d)^2. One block per bh.
// ---------------------------------------------------------------------------
__global__ __launch_bounds__(256)
void k_regfin(const float* __restrict__ Gpart, const float* __restrict__ invn,
              const float* __restrict__ nrmp,
              float* __restrict__ regp, float* __restrict__ t1p)
{
    const int bh = blockIdx.x;
    const int tid = threadIdx.x;
    float part = 0.f;
    for (int c = tid; c < 4096; c += 256) {
        const int d1 = c >> 6, d2 = c & 63;
        float g = 0.f;
        #pragma unroll
        for (int q = 0; q < 8; ++q)
            g += Gpart[(size_t)(bh * 8 + q) * 4096 + c];
        g *= invn[bh * 64 + d1] * invn[bh * 64 + d2];
        const float diff = g - ((d1 == d2) ? 1.f : 0.f);
        part = fmaf(diff, diff, part);
    }
    float t1l = 0.f;
    if (tid < 64) {
        float s = 0.f;
        #pragma unroll
        for (int t = 0; t < 16; ++t) s += nrmp[(size_t)(bh * 16 + t) * 64 + tid];
        const float iv = invn[bh * 64 + tid];
        t1l = s * iv * iv;
    }
    __shared__ float red[256];
    __shared__ float redT[256];
    red[tid] = part;
    redT[tid] = t1l;
    __syncthreads();
    for (int k = 128; k >= 1; k >>= 1) {
        if (tid < k) { red[tid] += red[tid + k]; redT[tid] += redT[tid + k]; }
        __syncthreads();
    }
    if (tid == 0) { regp[bh] = red[0]; t1p[bh] = redT[0]; }
}

// ---------------------------------------------------------------------------
extern "C" void kernel_launch(void* const* d_in, const int* in_sizes, int n_in,
                              void* d_out, int out_size, void* d_ws, size_t ws_size,
                              hipStream_t stream)
{
    const float* X  = (const float*)d_in[0];
    const float* Wq = (const float*)d_in[1];
    const float* bq = (const float*)d_in[2];
    const float* Wv = (const float*)d_in[3];
    const float* bv = (const float*)d_in[4];
    const float* Wo = (const float*)d_in[5];
    const float* bo = (const float*)d_in[6];

    float* out = (float*)d_out;
    float* att = out;                         // [4096,768]
    float* tr  = out + 3145728;
    float* rg  = out + 3145729;
    float* mq1 = out + 3145730;               // mixed_q (output 3)
    float* mq2 = out + 6291458;               // mixed_q (output 4)

    float* ws = (float*)d_ws;
    // Liveness-aliased layout (~25.8 MB):
    // mvb slot: mvb live until pass2; then WTo (1.2MB of 6MB slot).
    unsigned short* mvb  = (unsigned short*)(ws);             // [4096,768] bf16
    unsigned short* WTo  = (unsigned short*)(ws);             // after pass2
    // qb slot: qb live until pass2; then Gram partials (48*8*4096 floats).
    unsigned short* qb   = (unsigned short*)(ws + 1572864);   // [4096,768] bf16
    float*          Gpart = ws + 1572864;
    // vT slot: WTq/WTv live until k_gemm_qv; vT until k_regwt.
    unsigned short* vTslot = (unsigned short*)(ws + 3145728);
    unsigned short* WTq  = vTslot;
    unsigned short* WTv  = vTslot + 589824;
    unsigned short* vT   = vTslot;
    unsigned short* ctxb = (unsigned short*)(ws + 4718592);   // [4096,768] bf16
    float* nrmp = ws + 6291456;               // [768,64]
    float* aarr = ws + 6389760;               // [48,1024]
    float* invn = ws + 6438960;               // [48,64]
    float* t1p  = ws + 6442032;               // [48]
    float* t2p  = ws + 6442080;               // [768]
    float* regp = ws + 6442848;               // [48]

    if (ws_size < (size_t)6442896 * sizeof(float)) return;

    k_prep     <<<288,          256, 0, stream>>>(Wq, Wv, WTq, WTv);
    k_gemm_qv  <<<dim3(64, 12), 256, 0, stream>>>(X, WTq, WTv, bq, bv, mq1, mq2, qb, mvb);
    k_pass1T   <<<768,          256, 0, stream>>>(qb, mvb, vT, aarr, nrmp);
    k_pass2    <<<768,          256, 0, stream>>>(qb, vT, mvb, aarr, nrmp, invn, ctxb, t2p);
    k_regwt    <<<528,          256, 0, stream>>>(vT, Gpart, Wo, WTo);
    k_regfin   <<<48,           256, 0, stream>>>(Gpart, invn, nrmp, regp, t1p);
    k_gemm_one <<<769,          256, 0, stream>>>(ctxb, WTo, bo, att,
                                                  t1p, t2p, regp, tr, rg);
}

// Round 19
// 118.208 us; speedup vs baseline: 1.0409x; 1.0409x over previous
//
#include <hip/hip_runtime.h>
#include <math.h>

// Problem constants (ViT-Base): B=4, S=1024, D=768, H=12, HD=64
constexpr float SCALE = 0.125f;               // 1/sqrt(64)

typedef __attribute__((ext_vector_type(8))) short bf8;            // 8 bf16 (4 VGPRs)
typedef __attribute__((ext_vector_type(8))) unsigned short u16x8;
typedef __attribute__((ext_vector_type(4))) float f32x4;

static __device__ __forceinline__ unsigned short f2bf(float f) {
    unsigned int u = __float_as_uint(f);
    u += 0x7fffu + ((u >> 16) & 1u);          // round-to-nearest-even
    return (unsigned short)(u >> 16);
}
static __device__ __forceinline__ float bf2f(unsigned short h) {
    return __uint_as_float(((unsigned int)h) << 16);
}
static __device__ __forceinline__ bf8 ld8(const unsigned short* p) {
    return *reinterpret_cast<const bf8*>(p);
}
static __device__ __forceinline__ unsigned int cvtpk(float lo, float hi) {
    unsigned int r;
    asm("v_cvt_pk_bf16_f32 %0, %1, %2" : "=v"(r) : "v"(lo), "v"(hi));
    return r;
}

// ---------------------------------------------------------------------------
// Fused weight transpose+convert: Wq->WTq, Wv->WTv. 288 blocks flat.
// WT[n][k] = bf16(W[k][n])
// ---------------------------------------------------------------------------
__global__ __launch_bounds__(256)
void k_prep(const float* __restrict__ Wq, const float* __restrict__ Wv,
            unsigned short* __restrict__ WTq, unsigned short* __restrict__ WTv)
{
    __shared__ unsigned short T[64 * 72];
    const int bid = blockIdx.x;
    const bool isQ = (bid < 144);
    const int lb = isQ ? bid : bid - 144;
    const float* __restrict__ W = isQ ? Wq : Wv;
    unsigned short* __restrict__ WT = isQ ? WTq : WTv;
    const int n0 = (lb % 12) * 64;
    const int k0 = (lb / 12) * 64;
    const int tid = threadIdx.x;
    const int r  = tid >> 2;          // k within tile
    const int c0 = (tid & 3) * 16;    // n within tile
    const float* src = &W[(size_t)(k0 + r) * 768 + n0 + c0];
    #pragma unroll
    for (int q = 0; q < 4; ++q) {
        const float4 v = *reinterpret_cast<const float4*>(src + q * 4);
        uint2 pk;
        pk.x = cvtpk(v.x, v.y);
        pk.y = cvtpk(v.z, v.w);
        *reinterpret_cast<uint2*>(&T[r * 72 + c0 + q * 4]) = pk;
    }
    __syncthreads();
    const int n  = tid >> 2;          // n within tile
    const int kc = (tid & 3) * 16;    // k within tile
    u16x8 o0, o1;
    #pragma unroll
    for (int i = 0; i < 8; ++i) o0[i] = T[(kc + i) * 72 + n];
    #pragma unroll
    for (int i = 0; i < 8; ++i) o1[i] = T[(kc + 8 + i) * 72 + n];
    unsigned short* dst = WT + (size_t)(n0 + n) * 768 + k0 + kc;
    *reinterpret_cast<u16x8*>(dst)     = o0;
    *reinterpret_cast<u16x8*>(dst + 8) = o1;
}

// ---------------------------------------------------------------------------
// GEMM 1 (MFMA bf16): C = X @ WT^T + bias, A staged fp32->bf16 on the fly.
// Tile 64x128, grid (64,12) = 768 blocks, 4 waves (1x4).
// ---------------------------------------------------------------------------
__global__ __launch_bounds__(256)
void k_gemm_qv(const float* __restrict__ X,
               const unsigned short* __restrict__ WTq,
               const unsigned short* __restrict__ WTv,
               const float* __restrict__ bq, const float* __restrict__ bv,
               float* __restrict__ mq1, float* __restrict__ mq2,
               unsigned short* __restrict__ qb, unsigned short* __restrict__ mvb)
{
    __shared__ unsigned short As[64 * 72];
    __shared__ unsigned short Bs[128 * 72];
    const int m0 = blockIdx.x * 64;
    const bool isQ = (blockIdx.y < 6);
    const int n0 = (isQ ? blockIdx.y : blockIdx.y - 6) * 128;
    const unsigned short* __restrict__ WT = isQ ? WTq : WTv;
    const float* __restrict__ bias = isQ ? bq : bv;
    const int tid = threadIdx.x;
    const int wave = tid >> 6, lane = tid & 63, lm = lane & 15, lg = lane >> 4;
    const int wn = wave;

    f32x4 acc[4][2];
    #pragma unroll
    for (int mi = 0; mi < 4; ++mi)
        #pragma unroll
        for (int ni = 0; ni < 2; ++ni) acc[mi][ni] = (f32x4){0.f, 0.f, 0.f, 0.f};

    for (int k0 = 0; k0 < 768; k0 += 64) {
        #pragma unroll
        for (int it = 0; it < 4; ++it) {
            const int idx = tid + it * 256;
            const int arow = idx >> 4;
            const int ac4  = (idx & 15) * 4;
            const float4 v = *reinterpret_cast<const float4*>(
                &X[(size_t)(m0 + arow) * 768 + k0 + ac4]);
            uint2 pk;
            pk.x = cvtpk(v.x, v.y);
            pk.y = cvtpk(v.z, v.w);
            *reinterpret_cast<uint2*>(&As[arow * 72 + ac4]) = pk;
            const int brow = idx >> 3;
            const int bc8  = (idx & 7) * 8;
            *reinterpret_cast<u16x8*>(&Bs[brow * 72 + bc8]) =
                *reinterpret_cast<const u16x8*>(&WT[(size_t)(n0 + brow) * 768 + k0 + bc8]);
        }
        __syncthreads();
        #pragma unroll
        for (int ks = 0; ks < 2; ++ks) {
            bf8 af[4], bfr[2];
            #pragma unroll
            for (int mi = 0; mi < 4; ++mi)
                af[mi] = *reinterpret_cast<const bf8*>(
                    &As[(mi * 16 + lm) * 72 + ks * 32 + lg * 8]);
            #pragma unroll
            for (int ni = 0; ni < 2; ++ni)
                bfr[ni] = *reinterpret_cast<const bf8*>(
                    &Bs[(wn * 32 + ni * 16 + lm) * 72 + ks * 32 + lg * 8]);
            #pragma unroll
            for (int mi = 0; mi < 4; ++mi)
                #pragma unroll
                for (int ni = 0; ni < 2; ++ni)
                    acc[mi][ni] = __builtin_amdgcn_mfma_f32_16x16x32_bf16(
                        af[mi], bfr[ni], acc[mi][ni], 0, 0, 0);
        }
        __syncthreads();
    }
    #pragma unroll
    for (int ni = 0; ni < 2; ++ni) {
        const int c = n0 + wn * 32 + ni * 16 + lm;
        const float bcol = bias[c];
        #pragma unroll
        for (int mi = 0; mi < 4; ++mi)
            #pragma unroll
            for (int j = 0; j < 4; ++j) {
                const int r = m0 + mi * 16 + lg * 4 + j;
                const float v = acc[mi][ni][j] + bcol;
                const size_t off = (size_t)r * 768 + c;
                if (isQ) {
                    mq1[off] = v;
                    mq2[off] = v;
                    qb[off]  = f2bf(v);
                } else {
                    mvb[off] = f2bf(v);
                }
            }
    }
}

// ---------------------------------------------------------------------------
// GEMM 2 (MFMA bf16) + fused final reduction: flat grid 769.
// Blocks 0..767: att = ctxb @ WTo^T + bo (64x64 tile).
// Block 768: deterministic reduction of t1p/t2p/regp -> tr, reg scalars.
// ---------------------------------------------------------------------------
__global__ __launch_bounds__(256)
void k_gemm_one(const unsigned short* __restrict__ Xb,
                const unsigned short* __restrict__ WT,
                const float* __restrict__ bias, float* __restrict__ out,
                const float* __restrict__ t1p, const float* __restrict__ t2p,
                const float* __restrict__ regp, float* __restrict__ out_tr,
                float* __restrict__ out_reg)
{
    __shared__ unsigned short As[64 * 72];
    __shared__ unsigned short Bs[64 * 72];
    __shared__ float R1[256];
    __shared__ float R2[256];
    __shared__ float R3[256];
    const int tid = threadIdx.x;

    if (blockIdx.x == 768) {
        // ---- fused k_final -------------------------------------------------
        float s1 = 0.f, s2 = 0.f, s3 = 0.f;
        for (int i = tid; i < 768; i += 256) s2 += t2p[i];
        if (tid < 48) { s1 = t1p[tid]; s3 = regp[tid]; }
        R1[tid] = s1; R2[tid] = s2; R3[tid] = s3;
        __syncthreads();
        for (int w = 128; w >= 1; w >>= 1) {
            if (tid < w) { R1[tid] += R1[tid + w]; R2[tid] += R2[tid + w]; R3[tid] += R3[tid + w]; }
            __syncthreads();
        }
        if (tid == 0) {
            *out_tr  = fabsf(R1[0] - R2[0]) / 3072.f;
            *out_reg = R3[0] / 3072.f;
        }
        return;
    }

    const int m0 = (blockIdx.x & 63) * 64;
    const int n0 = (blockIdx.x >> 6) * 64;
    const int w = tid >> 6, lane = tid & 63, lm = lane & 15, lg = lane >> 4;

    f32x4 acc[4];
    #pragma unroll
    for (int ni = 0; ni < 4; ++ni) acc[ni] = (f32x4){0.f, 0.f, 0.f, 0.f};

    for (int k0 = 0; k0 < 768; k0 += 64) {
        #pragma unroll
        for (int it = 0; it < 2; ++it) {
            const int idx = tid + it * 256;
            const int row = idx >> 3;
            const int c8  = (idx & 7) * 8;
            *reinterpret_cast<u16x8*>(&As[row * 72 + c8]) =
                *reinterpret_cast<const u16x8*>(&Xb[(size_t)(m0 + row) * 768 + k0 + c8]);
            *reinterpret_cast<u16x8*>(&Bs[row * 72 + c8]) =
                *reinterpret_cast<const u16x8*>(&WT[(size_t)(n0 + row) * 768 + k0 + c8]);
        }
        __syncthreads();
        #pragma unroll
        for (int ks = 0; ks < 2; ++ks) {
            const bf8 af = *reinterpret_cast<const bf8*>(
                &As[(w * 16 + lm) * 72 + ks * 32 + lg * 8]);
            #pragma unroll
            for (int ni = 0; ni < 4; ++ni) {
                const bf8 bfr = *reinterpret_cast<const bf8*>(
                    &Bs[(ni * 16 + lm) * 72 + ks * 32 + lg * 8]);
                acc[ni] = __builtin_amdgcn_mfma_f32_16x16x32_bf16(af, bfr, acc[ni], 0, 0, 0);
            }
        }
        __syncthreads();
    }
    #pragma unroll
    for (int ni = 0; ni < 4; ++ni) {
        const int c = n0 + ni * 16 + lm;
        const float bcol = bias[c];
        #pragma unroll
        for (int j = 0; j < 4; ++j) {
            const int r = m0 + w * 16 + lg * 4 + j;
            out[(size_t)r * 768 + c] = acc[ni][j] + bcol;
        }
    }
}

// ---------------------------------------------------------------------------
// Pass 1 fused: V-tile transpose (mvb->vT) + column sumsq partials + QQ^T
// row-sums a_s = 1/(sum_t exp(sc/8)). LDS-staged K with BK=128 tiles
// (8 chunks, half the barriers), double-buffered. grid 768 flat, swizzled.
// ---------------------------------------------------------------------------
__global__ __launch_bounds__(256)
void k_pass1T(const unsigned short* __restrict__ qb,
              const unsigned short* __restrict__ mvb,
              unsigned short* __restrict__ vT,
              float* __restrict__ a, float* __restrict__ nrmp)
{
    __shared__ __align__(16) unsigned short Kb[2][128 * 72];
    const int bid = blockIdx.x;
    const int st = (bid >> 3) & 15;
    const int bh = (bid & 7) + 8 * (bid >> 7);
    const int b = bh / 12, h = bh % 12;
    const int s0 = st * 64;
    const int tid = threadIdx.x;
    const int w = tid >> 6, lane = tid & 63, lm = lane & 15, lg = lane >> 4;
    const size_t qoff = (size_t)(b * 1024) * 768 + h * 64;

    // ---- prologue: transpose V tile + norm partials (uses Kb[0] as scratch)
    {
        const int r  = tid >> 2;
        const int c0 = (tid & 3) * 16;
        const unsigned short* src = mvb + (size_t)(b * 1024 + s0 + r) * 768 + h * 64 + c0;
        const u16x8 x0 = *reinterpret_cast<const u16x8*>(src);
        const u16x8 x1 = *reinterpret_cast<const u16x8*>(src + 8);
        *reinterpret_cast<u16x8*>(&Kb[0][r * 72 + c0])     = x0;
        *reinterpret_cast<u16x8*>(&Kb[0][r * 72 + c0 + 8]) = x1;
        __syncthreads();
        const int dd  = tid >> 2;
        const int sc0 = (tid & 3) * 16;
        u16x8 o0, o1;
        float ps = 0.f;
        #pragma unroll
        for (int k = 0; k < 8; ++k) {
            o0[k] = Kb[0][(sc0 + k) * 72 + dd];
            const float v = bf2f(o0[k]);
            ps = fmaf(v, v, ps);
        }
        #pragma unroll
        for (int k = 0; k < 8; ++k) {
            o1[k] = Kb[0][(sc0 + 8 + k) * 72 + dd];
            const float v = bf2f(o1[k]);
            ps = fmaf(v, v, ps);
        }
        ps += __shfl_xor(ps, 1);
        ps += __shfl_xor(ps, 2);
        if ((tid & 3) == 0) nrmp[(size_t)(bh * 16 + st) * 64 + dd] = ps;
        unsigned short* dst = vT + (size_t)bh * 65536 + (size_t)dd * 1024 + s0 + sc0;
        *reinterpret_cast<u16x8*>(dst)     = o0;
        *reinterpret_cast<u16x8*>(dst + 8) = o1;
        __syncthreads();
    }

    // ---- pass1 main: QQ^T row sums over BK=128 tiles -----------------------
    const unsigned short* srow_p = qb + qoff + (size_t)(s0 + 16 * w + lm) * 768;
    const bf8 qs0 = ld8(srow_p + 8 * lg);
    const bf8 qs1 = ld8(srow_p + 32 + 8 * lg);
    const f32x4 z = {0.f, 0.f, 0.f, 0.f};
    float r = 0.f;

    u16x8 kr[4];
    #pragma unroll
    for (int it = 0; it < 4; ++it) {
        const int idx = tid + it * 256;
        kr[it] = *reinterpret_cast<const u16x8*>(
            qb + qoff + (size_t)(idx >> 3) * 768 + (idx & 7) * 8);
    }
    #pragma unroll
    for (int it = 0; it < 4; ++it) {
        const int idx = tid + it * 256;
        *reinterpret_cast<u16x8*>(&Kb[0][(idx >> 3) * 72 + (idx & 7) * 8]) = kr[it];
    }
    __syncthreads();
    int cur = 0;

    for (int tt = 0; tt < 8; ++tt) {
        const bool pf = (tt < 7);
        if (pf) {
            #pragma unroll
            for (int it = 0; it < 4; ++it) {
                const int idx = tid + it * 256;
                kr[it] = *reinterpret_cast<const u16x8*>(
                    qb + qoff + (size_t)((tt + 1) * 128 + (idx >> 3)) * 768 + (idx & 7) * 8);
            }
        }
        #pragma unroll
        for (int nf = 0; nf < 8; ++nf) {
            const bf8 ka0 = *reinterpret_cast<const bf8*>(
                &Kb[cur][(16 * nf + lm) * 72 + 8 * lg]);
            const bf8 ka1 = *reinterpret_cast<const bf8*>(
                &Kb[cur][(16 * nf + lm) * 72 + 32 + 8 * lg]);
            f32x4 ef = __builtin_amdgcn_mfma_f32_16x16x32_bf16(ka0, qs0, z, 0, 0, 0);
            ef = __builtin_amdgcn_mfma_f32_16x16x32_bf16(ka1, qs1, ef, 0, 0, 0);
            r += __expf(ef[0] * SCALE) + __expf(ef[1] * SCALE)
               + __expf(ef[2] * SCALE) + __expf(ef[3] * SCALE);
        }
        if (pf) {
            #pragma unroll
            for (int it = 0; it < 4; ++it) {
                const int idx = tid + it * 256;
                *reinterpret_cast<u16x8*>(
                    &Kb[cur ^ 1][(idx >> 3) * 72 + (idx & 7) * 8]) = kr[it];
            }
        }
        __syncthreads();
        cur ^= 1;
    }
    r += __shfl_xor(r, 16);
    r += __shfl_xor(r, 32);
    if (lg == 0) a[(size_t)bh * 1024 + s0 + 16 * w + lm] = 1.f / r;
}

// ---------------------------------------------------------------------------
// Pass 2 (MFMA, swapped QK + F-trick, LDS-staged K/V, double-buffered):
// F = E*(a_s+a_t); ctx = 0.5*F@V; dvec = 0.5*rowsum(F). invn computed in
// prologue from nrmp (st==0 blocks publish it to global for k_regfin).
// grid 768 flat, XCD-swizzled.
// ---------------------------------------------------------------------------
__global__ __launch_bounds__(256)
void k_pass2(const unsigned short* __restrict__ qb,
             const unsigned short* __restrict__ vT,
             const unsigned short* __restrict__ mvb,
             const float* __restrict__ a,
             const float* __restrict__ nrmp,
             float* __restrict__ invn_out,
             unsigned short* __restrict__ ctxb,
             float* __restrict__ t2p)
{
    __shared__ __align__(16) unsigned short Kb[2][64 * 72];
    __shared__ __align__(16) unsigned short Vb[2][64 * 72];
    __shared__ __align__(16) unsigned short F_lds[4 * 16 * 72];  // per-wave [16][72]
    __shared__ float red[256];
    __shared__ float inv_sh[64];
    const int bid = blockIdx.x;
    const int st = (bid >> 3) & 15;
    const int bh = (bid & 7) + 8 * (bid >> 7);
    const int b = bh / 12, h = bh % 12;
    const int s0 = st * 64;
    const int tid = threadIdx.x;
    const int w = tid >> 6, lane = tid & 63, lm = lane & 15, lg = lane >> 4;
    const size_t qoff = (size_t)(b * 1024) * 768 + h * 64;
    const unsigned short* srow_p = qb + qoff + (size_t)(s0 + 16 * w + lm) * 768;
    const bf8 qs0 = ld8(srow_p + 8 * lg);
    const bf8 qs1 = ld8(srow_p + 32 + 8 * lg);
    const unsigned short* vbase = vT + (size_t)bh * 65536;
    const float* abase = a + (size_t)bh * 1024;
    const float a_s = abase[s0 + 16 * w + lm];     // own-row a (A-operand row = lm)
    unsigned short* Frow = &F_lds[w * 1152 + lm * 72];  // lane's own s-row region
    const f32x4 z = {0.f, 0.f, 0.f, 0.f};
    f32x4 acc[4];
    #pragma unroll
    for (int nf = 0; nf < 4; ++nf) acc[nf] = z;
    float sF = 0.f;
    const int sr = tid >> 2;          // row within tile (t for K, d for V)
    const int sc = (tid & 3) << 4;    // 16-col group

    // invn from nrmp (tid<64); 16 independent L2 loads, overlapped w/ staging
    if (tid < 64) {
        float s = 0.f;
        #pragma unroll
        for (int t = 0; t < 16; ++t) s += nrmp[(size_t)(bh * 16 + t) * 64 + tid];
        const float iv = 1.f / fmaxf(sqrtf(s), 1e-12f);
        inv_sh[tid] = iv;
        if (st == 0) invn_out[bh * 64 + tid] = iv;
    }

    u16x8 kr0 = *reinterpret_cast<const u16x8*>(qb + qoff + (size_t)sr * 768 + sc);
    u16x8 kr1 = *reinterpret_cast<const u16x8*>(qb + qoff + (size_t)sr * 768 + sc + 8);
    u16x8 vr0 = *reinterpret_cast<const u16x8*>(vbase + (size_t)sr * 1024 + sc);
    u16x8 vr1 = *reinterpret_cast<const u16x8*>(vbase + (size_t)sr * 1024 + sc + 8);
    *reinterpret_cast<u16x8*>(&Kb[0][sr * 72 + sc])     = kr0;
    *reinterpret_cast<u16x8*>(&Kb[0][sr * 72 + sc + 8]) = kr1;
    *reinterpret_cast<u16x8*>(&Vb[0][sr * 72 + sc])     = vr0;
    *reinterpret_cast<u16x8*>(&Vb[0][sr * 72 + sc + 8]) = vr1;
    __syncthreads();
    int cur = 0;

    for (int tt = 0; tt < 16; ++tt) {
        const int t0 = tt * 64;
        if (tt < 15) {
            const size_t kg = qoff + (size_t)(t0 + 64 + sr) * 768 + sc;
            kr0 = *reinterpret_cast<const u16x8*>(qb + kg);
            kr1 = *reinterpret_cast<const u16x8*>(qb + kg + 8);
            const size_t vg = (size_t)sr * 1024 + t0 + 64 + sc;
            vr0 = *reinterpret_cast<const u16x8*>(vbase + vg);
            vr1 = *reinterpret_cast<const u16x8*>(vbase + vg + 8);
        }
        // ---- QK^T (swapped): lane holds sc[s=16w+lm][t=16nf+4lg+j] ---------
        f32x4 ef[4];
        #pragma unroll
        for (int nf = 0; nf < 4; ++nf) {
            const bf8 ka0 = *reinterpret_cast<const bf8*>(
                &Kb[cur][(16 * nf + lm) * 72 + 8 * lg]);
            const bf8 ka1 = *reinterpret_cast<const bf8*>(
                &Kb[cur][(16 * nf + lm) * 72 + 32 + 8 * lg]);
            ef[nf] = __builtin_amdgcn_mfma_f32_16x16x32_bf16(ka0, qs0, z, 0, 0, 0);
            ef[nf] = __builtin_amdgcn_mfma_f32_16x16x32_bf16(ka1, qs1, ef[nf], 0, 0, 0);
        }
        // ---- F = exp(sc/8)*(a_s + a_t); write own row to LDS ---------------
        #pragma unroll
        for (int nf = 0; nf < 4; ++nf) {
            const float4 af = *reinterpret_cast<const float4*>(
                abase + t0 + 16 * nf + 4 * lg);
            const float f0 = __expf(ef[nf][0] * SCALE) * (a_s + af.x);
            const float f1 = __expf(ef[nf][1] * SCALE) * (a_s + af.y);
            const float f2 = __expf(ef[nf][2] * SCALE) * (a_s + af.z);
            const float f3 = __expf(ef[nf][3] * SCALE) * (a_s + af.w);
            sF += (f0 + f1) + (f2 + f3);
            uint2 pk;
            pk.x = cvtpk(f0, f1);
            pk.y = cvtpk(f2, f3);
            *reinterpret_cast<uint2*>(&Frow[16 * nf + 4 * lg]) = pk;
        }
        // ---- PV: A-frag = own row from LDS (b128), B-frag = Vb LDS ---------
        #pragma unroll
        for (int ks = 0; ks < 2; ++ks) {
            const bf8 fa = *reinterpret_cast<const bf8*>(&Frow[32 * ks + 8 * lg]);
            #pragma unroll
            for (int nf = 0; nf < 4; ++nf) {
                const bf8 vfr = *reinterpret_cast<const bf8*>(
                    &Vb[cur][(16 * nf + lm) * 72 + 32 * ks + 8 * lg]);
                acc[nf] = __builtin_amdgcn_mfma_f32_16x16x32_bf16(fa, vfr, acc[nf], 0, 0, 0);
            }
        }
        if (tt < 15) {
            *reinterpret_cast<u16x8*>(&Kb[cur ^ 1][sr * 72 + sc])     = kr0;
            *reinterpret_cast<u16x8*>(&Kb[cur ^ 1][sr * 72 + sc + 8]) = kr1;
            *reinterpret_cast<u16x8*>(&Vb[cur ^ 1][sr * 72 + sc])     = vr0;
            *reinterpret_cast<u16x8*>(&Vb[cur ^ 1][sr * 72 + sc + 8]) = vr1;
        }
        __syncthreads();
        cur ^= 1;
    }
    sF += __shfl_xor(sF, 16);
    sF += __shfl_xor(sF, 32);

    float t2 = 0.f;
    #pragma unroll
    for (int j = 0; j < 4; ++j) {
        const int srow = s0 + 16 * w + 4 * lg + j;
        const float sFj = __shfl(sF, 4 * lg + j);
        const float rdv = 2.f / sFj;                // 1/dvec
        const size_t rowoff = (size_t)(b * 1024 + srow) * 768 + h * 64;
        #pragma unroll
        for (int nf = 0; nf < 4; ++nf) {
            const int d = lm + 16 * nf;
            const float iv = inv_sh[d];
            const float cf = 0.5f * acc[nf][j];
            ctxb[rowoff + d] = f2bf(cf);
            const float vv = bf2f(mvb[rowoff + d]);
            t2 = fmaf(vv * cf, iv * iv * rdv, t2);
        }
    }
    red[tid] = t2;
    __syncthreads();
    for (int k = 128; k >= 1; k >>= 1) {
        if (tid < k) red[tid] += red[tid + k];
        __syncthreads();
    }
    if (tid == 0) t2p[bh * 16 + st] = red[0];
}

// ---------------------------------------------------------------------------
// Merged: Gram partials (blocks 0..383) + Wo transpose (blocks 384..527).
// WTo is written into the (dead after pass2) mvb slot — no vT conflict.
// ---------------------------------------------------------------------------
__global__ __launch_bounds__(256)
void k_regwt(const unsigned short* __restrict__ vT, float* __restrict__ Gpart,
             const float* __restrict__ Wo, unsigned short* __restrict__ WTo)
{
    __shared__ unsigned short T[64 * 72];
    const int bid = blockIdx.x;
    const int tid = threadIdx.x;
    if (bid < 384) {
        // ---- Gram partial: bh = bid>>3, q = bid&7, K=128 slice --------------
        const int bh = bid >> 3;
        const int q  = bid & 7;
        const int w = tid >> 6, lane = tid & 63, lm = lane & 15, lg = lane >> 4;
        const unsigned short* base = vT + (size_t)bh * 65536;
        const unsigned short* arowp = base + (size_t)(16 * w + lm) * 1024;
        const f32x4 z = {0.f, 0.f, 0.f, 0.f};
        f32x4 acc[4];
        #pragma unroll
        for (int nf = 0; nf < 4; ++nf) acc[nf] = z;
        #pragma unroll
        for (int kk = 0; kk < 4; ++kk) {
            const int t0 = (q * 4 + kk) * 32 + 8 * lg;
            const bf8 av = ld8(arowp + t0);
            #pragma unroll
            for (int nf = 0; nf < 4; ++nf) {
                const bf8 bv = ld8(base + (size_t)(lm + 16 * nf) * 1024 + t0);
                acc[nf] = __builtin_amdgcn_mfma_f32_16x16x32_bf16(av, bv, acc[nf], 0, 0, 0);
            }
        }
        float* gdst = Gpart + (size_t)(bh * 8 + q) * 4096;
        #pragma unroll
        for (int nf = 0; nf < 4; ++nf) {
            const int d2 = lm + 16 * nf;
            #pragma unroll
            for (int j = 0; j < 4; ++j) {
                const int d1 = 16 * w + 4 * lg + j;
                gdst[d1 * 64 + d2] = acc[nf][j];
            }
        }
    } else {
        // ---- Wo transpose tile ----------------------------------------------
        const int lb = bid - 384;
        const int n0 = (lb % 12) * 64;
        const int k0 = (lb / 12) * 64;
        const int r  = tid >> 2;
        const int c0 = (tid & 3) * 16;
        const float* src = &Wo[(size_t)(k0 + r) * 768 + n0 + c0];
        #pragma unroll
        for (int q = 0; q < 4; ++q) {
            const float4 v = *reinterpret_cast<const float4*>(src + q * 4);
            uint2 pk;
            pk.x = cvtpk(v.x, v.y);
            pk.y = cvtpk(v.z, v.w);
            *reinterpret_cast<uint2*>(&T[r * 72 + c0 + q * 4]) = pk;
        }
        __syncthreads();
        const int n  = tid >> 2;
        const int kc = (tid & 3) * 16;
        u16x8 o0, o1;
        #pragma unroll
        for (int i = 0; i < 8; ++i) o0[i] = T[(kc + i) * 72 + n];
        #pragma unroll
        for (int i = 0; i < 8; ++i) o1[i] = T[(kc + 8 + i) * 72 + n];
        unsigned short* dst = WTo + (size_t)(n0 + n) * 768 + k0 + kc;
        *reinterpret_cast<u16x8*>(dst)     = o0;
        *reinterpret_cast<u16x8*>(dst + 8) = o1;
    }
}

// ---------------------------------------------------------------------------
// Gram finalize + t1: sum 8 Gram partials, scale by invn, sum (G - I)^2;
// also t1[bh] = sum_d nrmp_sum(d) * invn(d)^2. One block per bh.
// ---------------------------------------------------------------------------
__global__ __launch_bounds__(256)
void k_regfin(const float* __restrict__ Gpart, const float* __restrict__ invn,
              const float* __restrict__ nrmp,
              float* __restrict__ regp, float* __restrict__ t1p)
{
    const int bh = blockIdx.x;
    const int tid = threadIdx.x;
    float part = 0.f;
    for (int c = tid; c < 4096; c += 256) {
        const int d1 = c >> 6, d2 = c & 63;
        float g = 0.f;
        #pragma unroll
        for (int q = 0; q < 8; ++q)
            g += Gpart[(size_t)(bh * 8 + q) * 4096 + c];
        g *= invn[bh * 64 + d1] * invn[bh * 64 + d2];
        const float diff = g - ((d1 == d2) ? 1.f : 0.f);
        part = fmaf(diff, diff, part);
    }
    float t1l = 0.f;
    if (tid < 64) {
        float s = 0.f;
        #pragma unroll
        for (int t = 0; t < 16; ++t) s += nrmp[(size_t)(bh * 16 + t) * 64 + tid];
        const float iv = invn[bh * 64 + tid];
        t1l = s * iv * iv;
    }
    __shared__ float red[256];
    __shared__ float redT[256];
    red[tid] = part;
    redT[tid] = t1l;
    __syncthreads();
    for (int k = 128; k >= 1; k >>= 1) {
        if (tid < k) { red[tid] += red[tid + k]; redT[tid] += redT[tid + k]; }
        __syncthreads();
    }
    if (tid == 0) { regp[bh] = red[0]; t1p[bh] = redT[0]; }
}

// ---------------------------------------------------------------------------
extern "C" void kernel_launch(void* const* d_in, const int* in_sizes, int n_in,
                              void* d_out, int out_size, void* d_ws, size_t ws_size,
                              hipStream_t stream)
{
    const float* X  = (const float*)d_in[0];
    const float* Wq = (const float*)d_in[1];
    const float* bq = (const float*)d_in[2];
    const float* Wv = (const float*)d_in[3];
    const float* bv = (const float*)d_in[4];
    const float* Wo = (const float*)d_in[5];
    const float* bo = (const float*)d_in[6];

    float* out = (float*)d_out;
    float* att = out;                         // [4096,768]
    float* tr  = out + 3145728;
    float* rg  = out + 3145729;
    float* mq1 = out + 3145730;               // mixed_q (output 3)
    float* mq2 = out + 6291458;               // mixed_q (output 4)

    float* ws = (float*)d_ws;
    // Liveness-aliased layout (~25.8 MB):
    // mvb slot: mvb live until pass2; then WTo (1.2MB of 6MB slot).
    unsigned short* mvb  = (unsigned short*)(ws);             // [4096,768] bf16
    unsigned short* WTo  = (unsigned short*)(ws);             // after pass2
    // qb slot: qb live until pass2; then Gram partials (48*8*4096 floats).
    unsigned short* qb   = (unsigned short*)(ws + 1572864);   // [4096,768] bf16
    float*          Gpart = ws + 1572864;
    // vT slot: WTq/WTv live until k_gemm_qv; vT until k_regwt.
    unsigned short* vTslot = (unsigned short*)(ws + 3145728);
    unsigned short* WTq  = vTslot;
    unsigned short* WTv  = vTslot + 589824;
    unsigned short* vT   = vTslot;
    unsigned short* ctxb = (unsigned short*)(ws + 4718592);   // [4096,768] bf16
    float* nrmp = ws + 6291456;               // [768,64]
    float* aarr = ws + 6389760;               // [48,1024]
    float* invn = ws + 6438960;               // [48,64]
    float* t1p  = ws + 6442032;               // [48]
    float* t2p  = ws + 6442080;               // [768]
    float* regp = ws + 6442848;               // [48]

    if (ws_size < (size_t)6442896 * sizeof(float)) return;

    k_prep     <<<288,          256, 0, stream>>>(Wq, Wv, WTq, WTv);
    k_gemm_qv  <<<dim3(64, 12), 256, 0, stream>>>(X, WTq, WTv, bq, bv, mq1, mq2, qb, mvb);
    k_pass1T   <<<768,          256, 0, stream>>>(qb, mvb, vT, aarr, nrmp);
    k_pass2    <<<768,          256, 0, stream>>>(qb, vT, mvb, aarr, nrmp, invn, ctxb, t2p);
    k_regwt    <<<528,          256, 0, stream>>>(vT, Gpart, Wo, WTo);
    k_regfin   <<<48,           256, 0, stream>>>(Gpart, invn, nrmp, regp, t1p);
    k_gemm_one <<<769,          256, 0, stream>>>(ctxb, WTo, bo, att,
                                                  t1p, t2p, regp, tr, rg);
}